// Round 3
// baseline (4971.780 us; speedup 1.0000x reference)
//
#include <hip/hip_runtime.h>
#include <hip/hip_bf16.h>

// ---------------------------------------------------------------------------
// GraphSAGE distance estimator, fp32.
// Per encoder:
//   bucket-group edges by dst (LDS histogram -> deterministic scan -> LDS-
//   cursor scatter of (src,dst) pairs; bucket = contiguous 98-node range),
//   then per layer: Y = x@Wl ; A = bucketed LDS mean-aggregate(Y) ;
//   H = relu(A + bl + x@Wr)  (agg-add fused into the Wr GEMM epilogue).
//   pooled[b] = segment-sum over sorted batch (binary search, no atomics).
// Final: depth-norm + [S|G|d] @ W1 -> relu -> @ W2.
// ---------------------------------------------------------------------------

#define NB    1024   // dst buckets
#define EPB   32768  // edges per grouping block
#define BWMAX 128    // max nodes per bucket supported by agg LDS

// Per-block histogram of dst buckets (LDS atomics only).
__global__ __launch_bounds__(256) void p1_hist(const int* __restrict__ dst,
                                               int* __restrict__ blkhist,
                                               int E, int bw) {
    __shared__ int h[NB];
    for (int i = threadIdx.x; i < NB; i += 256) h[i] = 0;
    __syncthreads();
    const int base = blockIdx.x * EPB;
    for (int k = 0; k < EPB; k += 256) {
        const int e = base + k + threadIdx.x;
        if (e < E) atomicAdd(&h[dst[e] / bw], 1);
    }
    __syncthreads();
    for (int i = threadIdx.x; i < NB; i += 256)
        blkhist[(size_t)blockIdx.x * NB + i] = h[i];
}

// Turn blkhist[nblk][NB] into exact scatter bases: base[blk][b] and
// bucket_base[b] (exclusive prefix of bucket totals). Deterministic.
__global__ __launch_bounds__(NB) void p1_scan(const int* __restrict__ blkhist,
                                              int* __restrict__ basem,
                                              int* __restrict__ bucket_base,
                                              int nblk) {
    __shared__ int lds[NB];
    const int b = threadIdx.x;
    int s = 0;
    for (int k = 0; k < nblk; ++k) s += blkhist[(size_t)k * NB + b];
    lds[b] = s;
    __syncthreads();
    for (int off = 1; off < NB; off <<= 1) {
        int v = (b >= off) ? lds[b - off] : 0;
        __syncthreads();
        lds[b] += v;
        __syncthreads();
    }
    int run = lds[b] - s;  // exclusive prefix
    bucket_base[b] = run;
    if (b == NB - 1) bucket_base[NB] = run + s;
    for (int k = 0; k < nblk; ++k) {
        const int c = blkhist[(size_t)k * NB + b];
        basem[(size_t)k * NB + b] = run;
        run += c;
    }
}

// Scatter (src,dst) pairs to bucket-grouped layout. Each (block,bucket) run is
// contiguous (~256B), so L2 merges lines -> ~E*8B actual writes.
__global__ __launch_bounds__(256) void p1_scatter(const int* __restrict__ src,
                                                  const int* __restrict__ dst,
                                                  const int* __restrict__ basem,
                                                  int2* __restrict__ pairs,
                                                  int E, int bw) {
    __shared__ int cur[NB];
    for (int i = threadIdx.x; i < NB; i += 256)
        cur[i] = basem[(size_t)blockIdx.x * NB + i];
    __syncthreads();
    const int base = blockIdx.x * EPB;
    for (int k = 0; k < EPB; k += 256) {
        const int e = base + k + threadIdx.x;
        if (e < E) {
            const int d = dst[e];
            const int s = src[e];
            const int p = atomicAdd(&cur[d / bw], 1);
            pairs[p] = make_int2(s, d);
        }
    }
}

// One block per bucket: accumulate Y[src] rows into LDS fp32 accumulators,
// count degrees in LDS, write out the mean. 8 waves, 2-edge unroll.
__global__ __launch_bounds__(512) void agg_bucket(const float* __restrict__ Y,
                                                  const int2* __restrict__ pairs,
                                                  const int* __restrict__ bucket_base,
                                                  float* __restrict__ out,
                                                  int N, int bw) {
    __shared__ float acc[BWMAX * 64];
    __shared__ int scnt[BWMAX];
    const int b = blockIdx.x;
    const int lo = b * bw;
    int nn = N - lo;
    if (nn <= 0) return;
    if (nn > bw) nn = bw;
    const int tid = threadIdx.x, wid = tid >> 6, lane = tid & 63;
    for (int i = tid; i < nn * 64; i += 512) acc[i] = 0.0f;
    for (int i = tid; i < nn; i += 512) scnt[i] = 0;
    __syncthreads();
    const int e0 = bucket_base[b];
    const int e1 = bucket_base[b + 1];
    int e = e0 + wid * 2;
    for (; e + 2 <= e1; e += 16) {
        const int2 pA = pairs[e];
        const int2 pB = pairs[e + 1];
        const float vA = Y[(size_t)pA.x * 64 + lane];
        const float vB = Y[(size_t)pB.x * 64 + lane];
        atomicAdd(&acc[(pA.y - lo) * 64 + lane], vA);
        atomicAdd(&acc[(pB.y - lo) * 64 + lane], vB);
        if (lane == 0) {
            atomicAdd(&scnt[pA.y - lo], 1);
            atomicAdd(&scnt[pB.y - lo], 1);
        }
    }
    if (e < e1) {
        const int2 p = pairs[e];
        const float v = Y[(size_t)p.x * 64 + lane];
        atomicAdd(&acc[(p.y - lo) * 64 + lane], v);
        if (lane == 0) atomicAdd(&scnt[p.y - lo], 1);
    }
    __syncthreads();
    for (int i = wid; i < nn; i += 8) {
        float c = (float)scnt[i];
        if (c < 1.0f) c = 1.0f;
        out[(size_t)(lo + i) * 64 + lane] = acc[i * 64 + lane] / c;
    }
}

// out[r][j] = (relu?)( sum_k x[r][k]*W[k][j] + bias[j] + addv[r][j] )
template <int K>
__global__ __launch_bounds__(256) void gemm_rowwave(const float* __restrict__ x,
                                                    const float* __restrict__ W,
                                                    const float* __restrict__ addv,
                                                    const float* __restrict__ bias,
                                                    int do_relu,
                                                    float* __restrict__ out, int n) {
    __shared__ float ldsW[K * 64];
    __shared__ float ldsX[16 * K];
    const int tid = threadIdx.x;
    const int wid = tid >> 6;
    const int lane = tid & 63;
    {
        const float4* Wv = (const float4*)W;
        float4* Lv = (float4*)ldsW;
        for (int i = tid; i < K * 16; i += 256) Lv[i] = Wv[i];
    }
    const float bv = bias ? bias[lane] : 0.0f;
    __syncthreads();

    const int KC = K / 4;
    for (int base = blockIdx.x * 16; base < n; base += gridDim.x * 16) {
        {
            const float4* xv = (const float4*)(x + (size_t)base * K);
            float4* lx = (float4*)ldsX;
            int vrows = n - base; if (vrows > 16) vrows = 16;
            const int valid4 = vrows * KC;
            for (int i = tid; i < 16 * KC; i += 256)
                if (i < valid4) lx[i] = xv[i];
        }
        __syncthreads();
        float acc0 = 0.f, acc1 = 0.f, acc2 = 0.f, acc3 = 0.f;
        const float4* lxv = (const float4*)ldsX;
        #pragma unroll 4
        for (int kc = 0; kc < KC; ++kc) {
            const float w0 = ldsW[(kc * 4 + 0) * 64 + lane];
            const float w1 = ldsW[(kc * 4 + 1) * 64 + lane];
            const float w2 = ldsW[(kc * 4 + 2) * 64 + lane];
            const float w3 = ldsW[(kc * 4 + 3) * 64 + lane];
            const float4 x0 = lxv[(wid * 4 + 0) * KC + kc];
            const float4 x1 = lxv[(wid * 4 + 1) * KC + kc];
            const float4 x2 = lxv[(wid * 4 + 2) * KC + kc];
            const float4 x3 = lxv[(wid * 4 + 3) * KC + kc];
            acc0 += x0.x * w0 + x0.y * w1 + x0.z * w2 + x0.w * w3;
            acc1 += x1.x * w0 + x1.y * w1 + x1.z * w2 + x1.w * w3;
            acc2 += x2.x * w0 + x2.y * w1 + x2.z * w2 + x2.w * w3;
            acc3 += x3.x * w0 + x3.y * w1 + x3.z * w2 + x3.w * w3;
        }
        const int r = base + wid * 4;
        float accs[4] = {acc0, acc1, acc2, acc3};
        #pragma unroll
        for (int rr = 0; rr < 4; ++rr) {
            const int row = r + rr;
            if (row < n) {
                float v = accs[rr] + bv;
                if (addv) v += addv[(size_t)row * 64 + lane];
                if (do_relu) v = fmaxf(v, 0.0f);
                out[(size_t)row * 64 + lane] = v;
            }
        }
        __syncthreads();
    }
}

// batch is SORTED: one block per graph, binary-search the row range.
__global__ __launch_bounds__(256) void pool_seg(const float* __restrict__ H,
                                                const int* __restrict__ batch,
                                                float* __restrict__ pooled,
                                                int* __restrict__ pcnt, int n) {
    const int b = blockIdx.x;
    int lo = 0, hi = n;
    while (lo < hi) { int m = (lo + hi) >> 1; if (batch[m] < b) lo = m + 1; else hi = m; }
    const int beg = lo;
    hi = n;
    while (lo < hi) { int m = (lo + hi) >> 1; if (batch[m] < b + 1) lo = m + 1; else hi = m; }
    const int end = lo;

    const int wid = threadIdx.x >> 6;
    const int lane = threadIdx.x & 63;
    float acc = 0.f;
    for (int i = beg + wid; i < end; i += 4)
        acc += H[(size_t)i * 64 + lane];
    __shared__ float part[4][64];
    part[wid][lane] = acc;
    __syncthreads();
    if (wid == 0) {
        const float s = (part[0][lane] + part[1][lane]) + (part[2][lane] + part[3][lane]);
        pooled[(size_t)b * 64 + lane] = s;
        if (lane == 0) pcnt[b] = end - beg;
    }
}

__global__ __launch_bounds__(128) void final_mlp(const float* __restrict__ pooledS,
                                                 const int* __restrict__ cntS,
                                                 const float* __restrict__ pooledG,
                                                 const int* __restrict__ cntG,
                                                 const float* __restrict__ depth,
                                                 const float* __restrict__ W1,
                                                 const float* __restrict__ b1,
                                                 const float* __restrict__ W2,
                                                 const float* __restrict__ b2,
                                                 float* __restrict__ out, int Bn) {
    __shared__ float lW1[129 * 64];
    __shared__ float red[128];
    const int t = threadIdx.x;
    for (int i = t; i < 129 * 64; i += 128) lW1[i] = W1[i];
    const float d = (t < Bn) ? depth[t] : 0.0f;
    red[t] = d;
    __syncthreads();
    for (int off = 64; off > 0; off >>= 1) {
        if (t < off) red[t] += red[t + off];
        __syncthreads();
    }
    const float mean = red[0] / (float)Bn;
    __syncthreads();
    const float dev = d - mean;
    red[t] = (t < Bn) ? dev * dev : 0.0f;
    __syncthreads();
    for (int off = 64; off > 0; off >>= 1) {
        if (t < off) red[t] += red[t + off];
        __syncthreads();
    }
    const float stdv = sqrtf(red[0] / (float)Bn);
    const float dn = dev / (stdv + 1e-6f);
    if (t >= Bn) return;

    float acc[64];
    #pragma unroll
    for (int j = 0; j < 64; ++j) acc[j] = b1[j];
    int cs = cntS[t]; if (cs < 1) cs = 1;
    int cg = cntG[t]; if (cg < 1) cg = 1;
    const float invS = 1.0f / (float)cs;
    const float invG = 1.0f / (float)cg;
    const float* pS = pooledS + (size_t)t * 64;
    const float* pG = pooledG + (size_t)t * 64;
    for (int k = 0; k < 64; ++k) {
        const float fk = pS[k] * invS;
        #pragma unroll
        for (int j = 0; j < 64; ++j) acc[j] += fk * lW1[k * 64 + j];
    }
    for (int k = 0; k < 64; ++k) {
        const float fk = pG[k] * invG;
        #pragma unroll
        for (int j = 0; j < 64; ++j) acc[j] += fk * lW1[(64 + k) * 64 + j];
    }
    #pragma unroll
    for (int j = 0; j < 64; ++j) acc[j] += dn * lW1[128 * 64 + j];
    float o = b2[0];
    #pragma unroll
    for (int j = 0; j < 64; ++j) o += fmaxf(acc[j], 0.0f) * W2[j];
    out[t] = o;
}

static void run_encoder(const float* x, const int* ei, const int* batch,
                        const float* Wl1, const float* bl1, const float* Wr1,
                        const float* Wl2, const float* bl2, const float* Wr2,
                        float* bufA, float* bufB, float* bufC,
                        int2* pairs, int* blkhist, int* basem, int* bucket_base,
                        float* pooled, int* pcnt, int N, int E, int Bn, int bw,
                        int nblk, hipStream_t stream) {
    const int* src = ei;
    const int* dst = ei + E;
    p1_hist<<<nblk, 256, 0, stream>>>(dst, blkhist, E, bw);
    p1_scan<<<1, NB, 0, stream>>>(blkhist, basem, bucket_base, nblk);
    p1_scatter<<<nblk, 256, 0, stream>>>(src, dst, basem, pairs, E, bw);
    const int g16 = (N + 15) / 16;
    gemm_rowwave<128><<<g16, 256, 0, stream>>>(x, Wl1, nullptr, nullptr, 0, bufA, N);
    agg_bucket<<<NB, 512, 0, stream>>>(bufA, pairs, bucket_base, bufB, N, bw);
    gemm_rowwave<128><<<g16, 256, 0, stream>>>(x, Wr1, bufB, bl1, 1, bufC, N);
    gemm_rowwave<64><<<g16, 256, 0, stream>>>(bufC, Wl2, nullptr, nullptr, 0, bufA, N);
    agg_bucket<<<NB, 512, 0, stream>>>(bufA, pairs, bucket_base, bufB, N, bw);
    gemm_rowwave<64><<<g16, 256, 0, stream>>>(bufC, Wr2, bufB, bl2, 1, bufA, N);
    pool_seg<<<Bn, 256, 0, stream>>>(bufA, batch, pooled, pcnt, N);
}

extern "C" void kernel_launch(void* const* d_in, const int* in_sizes, int n_in,
                              void* d_out, int out_size, void* d_ws, size_t ws_size,
                              hipStream_t stream) {
    const float* state_x     = (const float*)d_in[0];
    const int*   state_ei    = (const int*)d_in[1];
    const int*   state_batch = (const int*)d_in[2];
    const float* goal_x      = (const float*)d_in[3];
    const int*   goal_ei     = (const int*)d_in[4];
    const int*   goal_batch  = (const int*)d_in[5];
    const float* depth       = (const float*)d_in[6];
    const float* s1_Wl = (const float*)d_in[7];
    const float* s1_bl = (const float*)d_in[8];
    const float* s1_Wr = (const float*)d_in[9];
    const float* s2_Wl = (const float*)d_in[10];
    const float* s2_bl = (const float*)d_in[11];
    const float* s2_Wr = (const float*)d_in[12];
    const float* g1_Wl = (const float*)d_in[13];
    const float* g1_bl = (const float*)d_in[14];
    const float* g1_Wr = (const float*)d_in[15];
    const float* g2_Wl = (const float*)d_in[16];
    const float* g2_bl = (const float*)d_in[17];
    const float* g2_Wr = (const float*)d_in[18];
    const float* mlp_W1 = (const float*)d_in[19];
    const float* mlp_b1 = (const float*)d_in[20];
    const float* mlp_W2 = (const float*)d_in[21];
    const float* mlp_b2 = (const float*)d_in[22];

    const int N  = in_sizes[0] / 128;
    const int E  = in_sizes[1] / 2;
    const int Bn = in_sizes[6];
    const int bw = (N + NB - 1) / NB;         // nodes per bucket
    const int nblk = (E + EPB - 1) / EPB;     // grouping blocks

    char* w = (char*)d_ws;
    auto alloc = [&](size_t bytes) {
        char* p = w;
        w += (bytes + 255) & ~(size_t)255;
        return p;
    };
    float* bufA        = (float*)alloc((size_t)N * 64 * sizeof(float));
    float* bufB        = (float*)alloc((size_t)N * 64 * sizeof(float));
    float* bufC        = (float*)alloc((size_t)N * 64 * sizeof(float));
    int2*  pairs       = (int2*)alloc((size_t)E * sizeof(int2));
    int*   blkhist     = (int*)alloc((size_t)nblk * NB * sizeof(int));
    int*   basem       = (int*)alloc((size_t)nblk * NB * sizeof(int));
    int*   bucket_base = (int*)alloc((size_t)(NB + 1) * sizeof(int));
    float* pooledS     = (float*)alloc((size_t)Bn * 64 * sizeof(float));
    float* pooledG     = (float*)alloc((size_t)Bn * 64 * sizeof(float));
    int*   cntS        = (int*)alloc((size_t)Bn * sizeof(int));
    int*   cntG        = (int*)alloc((size_t)Bn * sizeof(int));
    const size_t need = (size_t)(w - (char*)d_ws);
    if (need > ws_size || bw > BWMAX) {  // fail loudly with zeros
        hipMemsetAsync(d_out, 0, (size_t)out_size * sizeof(float), stream);
        return;
    }

    run_encoder(state_x, state_ei, state_batch, s1_Wl, s1_bl, s1_Wr, s2_Wl, s2_bl, s2_Wr,
                bufA, bufB, bufC, pairs, blkhist, basem, bucket_base,
                pooledS, cntS, N, E, Bn, bw, nblk, stream);
    run_encoder(goal_x, goal_ei, goal_batch, g1_Wl, g1_bl, g1_Wr, g2_Wl, g2_bl, g2_Wr,
                bufA, bufB, bufC, pairs, blkhist, basem, bucket_base,
                pooledG, cntG, N, E, Bn, bw, nblk, stream);

    final_mlp<<<1, 128, 0, stream>>>(pooledS, cntS, pooledG, cntG, depth,
                                     mlp_W1, mlp_b1, mlp_W2, mlp_b2, (float*)d_out, Bn);
}

// Round 4
// 1194.690 us; speedup vs baseline: 4.1616x; 4.1616x over previous
//
#include <hip/hip_runtime.h>
#include <hip/hip_bf16.h>

// ---------------------------------------------------------------------------
// GraphSAGE distance estimator, fp32.
// Per encoder:
//   edge grouping: LDS bucket histogram -> deterministic scan -> bucket-
//   grouped (src,dst) scatter (contiguous writes) -> per-bucket LDS counting
//   sort into a true dst-sorted CSR (+row_start), writes confined to an
//   L2-resident 12.5KB window per bucket (no write amplification).
//   per layer: Y = x@Wl ; A = csr mean-aggregate(Y) [wave/node, reg acc] ;
//   H = relu(A + bl + x@Wr)  (agg-add fused into Wr GEMM epilogue).
//   pooled[b] = segment-sum over sorted batch (binary search, no atomics).
// Final: depth-norm + [S|G|d] @ W1 -> relu -> @ W2.
// ---------------------------------------------------------------------------

#define NB    1024   // dst buckets
#define EPB   16384  // edges per grouping block
#define BWMAX 128    // max nodes per bucket supported by sort LDS

// Per-block histogram of dst buckets (LDS atomics only).
__global__ __launch_bounds__(256) void p1_hist(const int* __restrict__ dst,
                                               int* __restrict__ blkhist,
                                               int E, int bw) {
    __shared__ int h[NB];
    for (int i = threadIdx.x; i < NB; i += 256) h[i] = 0;
    __syncthreads();
    const int base = blockIdx.x * EPB;
    for (int k = 0; k < EPB; k += 256) {
        const int e = base + k + threadIdx.x;
        if (e < E) atomicAdd(&h[dst[e] / bw], 1);
    }
    __syncthreads();
    for (int i = threadIdx.x; i < NB; i += 256)
        blkhist[(size_t)blockIdx.x * NB + i] = h[i];
}

// blkhist[nblk][NB] -> exact scatter bases basem[blk][b], bucket_base[b].
__global__ __launch_bounds__(NB) void p1_scan(const int* __restrict__ blkhist,
                                              int* __restrict__ basem,
                                              int* __restrict__ bucket_base,
                                              int nblk) {
    __shared__ int lds[NB];
    const int b = threadIdx.x;
    int s = 0;
    for (int k = 0; k < nblk; ++k) s += blkhist[(size_t)k * NB + b];
    lds[b] = s;
    __syncthreads();
    for (int off = 1; off < NB; off <<= 1) {
        int v = (b >= off) ? lds[b - off] : 0;
        __syncthreads();
        lds[b] += v;
        __syncthreads();
    }
    int run = lds[b] - s;  // exclusive prefix
    bucket_base[b] = run;
    if (b == NB - 1) bucket_base[NB] = run + s;
    for (int k = 0; k < nblk; ++k) {
        const int c = blkhist[(size_t)k * NB + b];
        basem[(size_t)k * NB + b] = run;
        run += c;
    }
}

// Scatter (src,dst) pairs to bucket-grouped layout; per-(block,bucket) runs
// are contiguous so L2 merges full lines.
__global__ __launch_bounds__(256) void p1_scatter(const int* __restrict__ src,
                                                  const int* __restrict__ dst,
                                                  const int* __restrict__ basem,
                                                  int2* __restrict__ pairs,
                                                  int E, int bw) {
    __shared__ int cur[NB];
    for (int i = threadIdx.x; i < NB; i += 256)
        cur[i] = basem[(size_t)blockIdx.x * NB + i];
    __syncthreads();
    const int base = blockIdx.x * EPB;
    for (int k = 0; k < EPB; k += 256) {
        const int e = base + k + threadIdx.x;
        if (e < E) {
            const int d = dst[e];
            const int s = src[e];
            const int p = atomicAdd(&cur[d / bw], 1);
            pairs[p] = make_int2(s, d);
        }
    }
}

// Per-bucket LDS counting sort -> dst-sorted csr (src ids) + row_start.
// All csr writes for a bucket land in a ~12.5KB window (L2 resident).
__global__ __launch_bounds__(512) void p2_sort(const int2* __restrict__ pairs,
                                               const int* __restrict__ bucket_base,
                                               int* __restrict__ csr,
                                               int* __restrict__ row_start,
                                               int N, int bw) {
    __shared__ int cnt[BWMAX];
    __shared__ int off[BWMAX];
    const int b = blockIdx.x;
    const int lo = b * bw;
    int nn = N - lo;
    if (nn <= 0) return;
    if (nn > bw) nn = bw;
    const int tid = threadIdx.x;
    for (int i = tid; i < nn; i += 512) cnt[i] = 0;
    __syncthreads();
    const int e0 = bucket_base[b];
    const int e1 = bucket_base[b + 1];
    for (int e = e0 + tid; e < e1; e += 512)
        atomicAdd(&cnt[pairs[e].y - lo], 1);
    __syncthreads();
    if (tid == 0) {
        int run = e0;
        for (int i = 0; i < nn; ++i) { off[i] = run; run += cnt[i]; }
    }
    __syncthreads();
    for (int i = tid; i < nn; i += 512) {
        row_start[lo + i] = off[i];
        cnt[i] = off[i];  // reuse as cursor
    }
    if (lo + nn == N && tid == 0) row_start[N] = e1;
    __syncthreads();
    for (int e = e0 + tid; e < e1; e += 512) {
        const int2 p = pairs[e];
        const int pos = atomicAdd(&cnt[p.y - lo], 1);
        csr[pos] = p.x;
    }
}

// Wave per destination node: lane j accumulates feature j; 8 independent
// gathers in flight to hide L2/L3 latency.
__global__ __launch_bounds__(256) void agg_mean(const float* __restrict__ Y,
                                                const int* __restrict__ csr,
                                                const int* __restrict__ row_start,
                                                float* __restrict__ out, int n) {
    const int wid = threadIdx.x >> 6;
    const int lane = threadIdx.x & 63;
    for (int i = blockIdx.x * 4 + wid; i < n; i += gridDim.x * 4) {
        const int r0 = __builtin_amdgcn_readfirstlane(row_start[i]);
        const int r1 = __builtin_amdgcn_readfirstlane(row_start[i + 1]);
        float a0 = 0.f, a1 = 0.f, a2 = 0.f, a3 = 0.f;
        float a4 = 0.f, a5 = 0.f, a6 = 0.f, a7 = 0.f;
        int e = r0;
        for (; e + 8 <= r1; e += 8) {
            const int s0 = csr[e],     s1 = csr[e + 1], s2 = csr[e + 2], s3 = csr[e + 3];
            const int s4 = csr[e + 4], s5 = csr[e + 5], s6 = csr[e + 6], s7 = csr[e + 7];
            a0 += Y[(size_t)s0 * 64 + lane];
            a1 += Y[(size_t)s1 * 64 + lane];
            a2 += Y[(size_t)s2 * 64 + lane];
            a3 += Y[(size_t)s3 * 64 + lane];
            a4 += Y[(size_t)s4 * 64 + lane];
            a5 += Y[(size_t)s5 * 64 + lane];
            a6 += Y[(size_t)s6 * 64 + lane];
            a7 += Y[(size_t)s7 * 64 + lane];
        }
        for (; e < r1; ++e) a0 += Y[(size_t)csr[e] * 64 + lane];
        const float acc = ((a0 + a1) + (a2 + a3)) + ((a4 + a5) + (a6 + a7));
        const int c = r1 - r0;
        const float sc = (c > 0) ? (1.0f / (float)c) : 1.0f;
        out[(size_t)i * 64 + lane] = acc * sc;
    }
}

// out[r][j] = (relu?)( sum_k x[r][k]*W[k][j] + bias[j] + addv[r][j] )
template <int K>
__global__ __launch_bounds__(256) void gemm_rowwave(const float* __restrict__ x,
                                                    const float* __restrict__ W,
                                                    const float* __restrict__ addv,
                                                    const float* __restrict__ bias,
                                                    int do_relu,
                                                    float* __restrict__ out, int n) {
    __shared__ float ldsW[K * 64];
    __shared__ float ldsX[16 * K];
    const int tid = threadIdx.x;
    const int wid = tid >> 6;
    const int lane = tid & 63;
    {
        const float4* Wv = (const float4*)W;
        float4* Lv = (float4*)ldsW;
        for (int i = tid; i < K * 16; i += 256) Lv[i] = Wv[i];
    }
    const float bv = bias ? bias[lane] : 0.0f;
    __syncthreads();

    const int KC = K / 4;
    for (int base = blockIdx.x * 16; base < n; base += gridDim.x * 16) {
        {
            const float4* xv = (const float4*)(x + (size_t)base * K);
            float4* lx = (float4*)ldsX;
            int vrows = n - base; if (vrows > 16) vrows = 16;
            const int valid4 = vrows * KC;
            for (int i = tid; i < 16 * KC; i += 256)
                if (i < valid4) lx[i] = xv[i];
        }
        __syncthreads();
        float acc0 = 0.f, acc1 = 0.f, acc2 = 0.f, acc3 = 0.f;
        const float4* lxv = (const float4*)ldsX;
        #pragma unroll 4
        for (int kc = 0; kc < KC; ++kc) {
            const float w0 = ldsW[(kc * 4 + 0) * 64 + lane];
            const float w1 = ldsW[(kc * 4 + 1) * 64 + lane];
            const float w2 = ldsW[(kc * 4 + 2) * 64 + lane];
            const float w3 = ldsW[(kc * 4 + 3) * 64 + lane];
            const float4 x0 = lxv[(wid * 4 + 0) * KC + kc];
            const float4 x1 = lxv[(wid * 4 + 1) * KC + kc];
            const float4 x2 = lxv[(wid * 4 + 2) * KC + kc];
            const float4 x3 = lxv[(wid * 4 + 3) * KC + kc];
            acc0 += x0.x * w0 + x0.y * w1 + x0.z * w2 + x0.w * w3;
            acc1 += x1.x * w0 + x1.y * w1 + x1.z * w2 + x1.w * w3;
            acc2 += x2.x * w0 + x2.y * w1 + x2.z * w2 + x2.w * w3;
            acc3 += x3.x * w0 + x3.y * w1 + x3.z * w2 + x3.w * w3;
        }
        const int r = base + wid * 4;
        float accs[4] = {acc0, acc1, acc2, acc3};
        #pragma unroll
        for (int rr = 0; rr < 4; ++rr) {
            const int row = r + rr;
            if (row < n) {
                float v = accs[rr] + bv;
                if (addv) v += addv[(size_t)row * 64 + lane];
                if (do_relu) v = fmaxf(v, 0.0f);
                out[(size_t)row * 64 + lane] = v;
            }
        }
        __syncthreads();
    }
}

// batch is SORTED: one block per graph, binary-search the row range.
__global__ __launch_bounds__(256) void pool_seg(const float* __restrict__ H,
                                                const int* __restrict__ batch,
                                                float* __restrict__ pooled,
                                                int* __restrict__ pcnt, int n) {
    const int b = blockIdx.x;
    int lo = 0, hi = n;
    while (lo < hi) { int m = (lo + hi) >> 1; if (batch[m] < b) lo = m + 1; else hi = m; }
    const int beg = lo;
    hi = n;
    while (lo < hi) { int m = (lo + hi) >> 1; if (batch[m] < b + 1) lo = m + 1; else hi = m; }
    const int end = lo;

    const int wid = threadIdx.x >> 6;
    const int lane = threadIdx.x & 63;
    float acc = 0.f;
    for (int i = beg + wid; i < end; i += 4)
        acc += H[(size_t)i * 64 + lane];
    __shared__ float part[4][64];
    part[wid][lane] = acc;
    __syncthreads();
    if (wid == 0) {
        const float s = (part[0][lane] + part[1][lane]) + (part[2][lane] + part[3][lane]);
        pooled[(size_t)b * 64 + lane] = s;
        if (lane == 0) pcnt[b] = end - beg;
    }
}

__global__ __launch_bounds__(128) void final_mlp(const float* __restrict__ pooledS,
                                                 const int* __restrict__ cntS,
                                                 const float* __restrict__ pooledG,
                                                 const int* __restrict__ cntG,
                                                 const float* __restrict__ depth,
                                                 const float* __restrict__ W1,
                                                 const float* __restrict__ b1,
                                                 const float* __restrict__ W2,
                                                 const float* __restrict__ b2,
                                                 float* __restrict__ out, int Bn) {
    __shared__ float lW1[129 * 64];
    __shared__ float red[128];
    const int t = threadIdx.x;
    for (int i = t; i < 129 * 64; i += 128) lW1[i] = W1[i];
    const float d = (t < Bn) ? depth[t] : 0.0f;
    red[t] = d;
    __syncthreads();
    for (int off = 64; off > 0; off >>= 1) {
        if (t < off) red[t] += red[t + off];
        __syncthreads();
    }
    const float mean = red[0] / (float)Bn;
    __syncthreads();
    const float dev = d - mean;
    red[t] = (t < Bn) ? dev * dev : 0.0f;
    __syncthreads();
    for (int off = 64; off > 0; off >>= 1) {
        if (t < off) red[t] += red[t + off];
        __syncthreads();
    }
    const float stdv = sqrtf(red[0] / (float)Bn);
    const float dn = dev / (stdv + 1e-6f);
    if (t >= Bn) return;

    float acc[64];
    #pragma unroll
    for (int j = 0; j < 64; ++j) acc[j] = b1[j];
    int cs = cntS[t]; if (cs < 1) cs = 1;
    int cg = cntG[t]; if (cg < 1) cg = 1;
    const float invS = 1.0f / (float)cs;
    const float invG = 1.0f / (float)cg;
    const float* pS = pooledS + (size_t)t * 64;
    const float* pG = pooledG + (size_t)t * 64;
    for (int k = 0; k < 64; ++k) {
        const float fk = pS[k] * invS;
        #pragma unroll
        for (int j = 0; j < 64; ++j) acc[j] += fk * lW1[k * 64 + j];
    }
    for (int k = 0; k < 64; ++k) {
        const float fk = pG[k] * invG;
        #pragma unroll
        for (int j = 0; j < 64; ++j) acc[j] += fk * lW1[(64 + k) * 64 + j];
    }
    #pragma unroll
    for (int j = 0; j < 64; ++j) acc[j] += dn * lW1[128 * 64 + j];
    float o = b2[0];
    #pragma unroll
    for (int j = 0; j < 64; ++j) o += fmaxf(acc[j], 0.0f) * W2[j];
    out[t] = o;
}

static void run_encoder(const float* x, const int* ei, const int* batch,
                        const float* Wl1, const float* bl1, const float* Wr1,
                        const float* Wl2, const float* bl2, const float* Wr2,
                        float* bufA, float* bufB, float* bufC,
                        int* csr, int* row_start, int* blkhist, int* basem,
                        int* bucket_base, float* pooled, int* pcnt,
                        int N, int E, int Bn, int bw, int nblk,
                        hipStream_t stream) {
    const int* src = ei;
    const int* dst = ei + E;
    int2* pairs = (int2*)bufC;  // dead before first gemm writes bufC
    p1_hist<<<nblk, 256, 0, stream>>>(dst, blkhist, E, bw);
    p1_scan<<<1, NB, 0, stream>>>(blkhist, basem, bucket_base, nblk);
    p1_scatter<<<nblk, 256, 0, stream>>>(src, dst, basem, pairs, E, bw);
    p2_sort<<<NB, 512, 0, stream>>>(pairs, bucket_base, csr, row_start, N, bw);
    const int g16 = (N + 15) / 16;
    const int g4 = (N + 3) / 4;
    // Y1 = x@Wl1 -> A ; A1 = agg -> B ; H1 = relu(A1+bl1+x@Wr1) -> C
    gemm_rowwave<128><<<g16, 256, 0, stream>>>(x, Wl1, nullptr, nullptr, 0, bufA, N);
    agg_mean<<<g4, 256, 0, stream>>>(bufA, csr, row_start, bufB, N);
    gemm_rowwave<128><<<g16, 256, 0, stream>>>(x, Wr1, bufB, bl1, 1, bufC, N);
    // Y2 = H1@Wl2 -> A ; A2 = agg -> B ; H2 = relu(A2+bl2+H1@Wr2) -> A
    gemm_rowwave<64><<<g16, 256, 0, stream>>>(bufC, Wl2, nullptr, nullptr, 0, bufA, N);
    agg_mean<<<g4, 256, 0, stream>>>(bufA, csr, row_start, bufB, N);
    gemm_rowwave<64><<<g16, 256, 0, stream>>>(bufC, Wr2, bufB, bl2, 1, bufA, N);
    pool_seg<<<Bn, 256, 0, stream>>>(bufA, batch, pooled, pcnt, N);
}

extern "C" void kernel_launch(void* const* d_in, const int* in_sizes, int n_in,
                              void* d_out, int out_size, void* d_ws, size_t ws_size,
                              hipStream_t stream) {
    const float* state_x     = (const float*)d_in[0];
    const int*   state_ei    = (const int*)d_in[1];
    const int*   state_batch = (const int*)d_in[2];
    const float* goal_x      = (const float*)d_in[3];
    const int*   goal_ei     = (const int*)d_in[4];
    const int*   goal_batch  = (const int*)d_in[5];
    const float* depth       = (const float*)d_in[6];
    const float* s1_Wl = (const float*)d_in[7];
    const float* s1_bl = (const float*)d_in[8];
    const float* s1_Wr = (const float*)d_in[9];
    const float* s2_Wl = (const float*)d_in[10];
    const float* s2_bl = (const float*)d_in[11];
    const float* s2_Wr = (const float*)d_in[12];
    const float* g1_Wl = (const float*)d_in[13];
    const float* g1_bl = (const float*)d_in[14];
    const float* g1_Wr = (const float*)d_in[15];
    const float* g2_Wl = (const float*)d_in[16];
    const float* g2_bl = (const float*)d_in[17];
    const float* g2_Wr = (const float*)d_in[18];
    const float* mlp_W1 = (const float*)d_in[19];
    const float* mlp_b1 = (const float*)d_in[20];
    const float* mlp_W2 = (const float*)d_in[21];
    const float* mlp_b2 = (const float*)d_in[22];

    const int N  = in_sizes[0] / 128;
    const int E  = in_sizes[1] / 2;
    const int Bn = in_sizes[6];
    const int bw = (N + NB - 1) / NB;         // nodes per bucket
    const int nblk = (E + EPB - 1) / EPB;     // grouping blocks

    char* w = (char*)d_ws;
    auto alloc = [&](size_t bytes) {
        char* p = w;
        w += (bytes + 255) & ~(size_t)255;
        return p;
    };
    float* bufA        = (float*)alloc((size_t)N * 64 * sizeof(float));
    float* bufB        = (float*)alloc((size_t)N * 64 * sizeof(float));
    float* bufC        = (float*)alloc((size_t)N * 64 * sizeof(float));  // aliases pairs
    int*   csr         = (int*)alloc((size_t)E * sizeof(int));
    int*   row_start   = (int*)alloc((size_t)(N + 1) * sizeof(int));
    int*   blkhist     = (int*)alloc((size_t)nblk * NB * sizeof(int));
    int*   basem       = (int*)alloc((size_t)nblk * NB * sizeof(int));
    int*   bucket_base = (int*)alloc((size_t)(NB + 1) * sizeof(int));
    float* pooledS     = (float*)alloc((size_t)Bn * 64 * sizeof(float));
    float* pooledG     = (float*)alloc((size_t)Bn * 64 * sizeof(float));
    int*   cntS        = (int*)alloc((size_t)Bn * sizeof(int));
    int*   cntG        = (int*)alloc((size_t)Bn * sizeof(int));
    const size_t need = (size_t)(w - (char*)d_ws);
    if (need > ws_size || bw > BWMAX || (size_t)E * sizeof(int2) > (size_t)N * 64 * sizeof(float)) {
        hipMemsetAsync(d_out, 0, (size_t)out_size * sizeof(float), stream);
        return;
    }

    run_encoder(state_x, state_ei, state_batch, s1_Wl, s1_bl, s1_Wr, s2_Wl, s2_bl, s2_Wr,
                bufA, bufB, bufC, csr, row_start, blkhist, basem, bucket_base,
                pooledS, cntS, N, E, Bn, bw, nblk, stream);
    run_encoder(goal_x, goal_ei, goal_batch, g1_Wl, g1_bl, g1_Wr, g2_Wl, g2_bl, g2_Wr,
                bufA, bufB, bufC, csr, row_start, blkhist, basem, bucket_base,
                pooledG, cntG, N, E, Bn, bw, nblk, stream);

    final_mlp<<<1, 128, 0, stream>>>(pooledS, cntS, pooledG, cntG, depth,
                                     mlp_W1, mlp_b1, mlp_W2, mlp_b2, (float*)d_out, Bn);
}

// Round 5
// 1030.474 us; speedup vs baseline: 4.8248x; 1.1594x over previous
//
#include <hip/hip_runtime.h>
#include <hip/hip_bf16.h>

// ---------------------------------------------------------------------------
// GraphSAGE distance estimator, fp32.
//   CSR build (both graphs batched): LDS bucket hist -> scan -> bucket-grouped
//   scatter -> per-bucket LDS counting sort (pow2 bucket width, no int div).
//   Per layer: {Y,R} = x@{Wl,Wr} in ONE fused GEMM (x via wave-uniform scalar
//   loads, W in LDS); H = relu(csr-mean(Y) + bl + R) fused into aggregate.
//   Pool: 8 partial blocks per graph (binary search, no atomics), combined in
//   final_mlp.
// ---------------------------------------------------------------------------

#define NB    1024   // dst buckets (pow2)
#define EPB   16384  // edges per grouping block
#define BWMAX 128    // max nodes per bucket (LDS arrays in sort)
#define PP    8      // pool partials per graph

// ---- CSR build (batched over both graphs) ----------------------------------

__global__ __launch_bounds__(256) void p1_hist(const int* __restrict__ dstS,
                                               const int* __restrict__ dstG,
                                               int* __restrict__ blkhist,
                                               int E, int bsh, int nblk) {
    const int g = blockIdx.x / nblk;
    const int blk = blockIdx.x % nblk;
    const int* __restrict__ dst = g ? dstG : dstS;
    __shared__ int h[NB];
    for (int i = threadIdx.x; i < NB; i += 256) h[i] = 0;
    __syncthreads();
    const int base = blk * EPB;
    for (int k = 0; k < EPB; k += 256) {
        const int e = base + k + threadIdx.x;
        if (e < E) atomicAdd(&h[dst[e] >> bsh], 1);
    }
    __syncthreads();
    for (int i = threadIdx.x; i < NB; i += 256)
        blkhist[((size_t)(g * nblk + blk)) * NB + i] = h[i];
}

__global__ __launch_bounds__(NB) void p1_scan(const int* __restrict__ blkhist,
                                              int* __restrict__ basem,
                                              int* __restrict__ bucket_base,
                                              int nblk) {
    __shared__ int lds[NB];
    const int g = blockIdx.x;
    const int* __restrict__ bh = blkhist + (size_t)g * nblk * NB;
    int* __restrict__ bm = basem + (size_t)g * nblk * NB;
    int* __restrict__ bb = bucket_base + (size_t)g * (NB + 1);
    const int b = threadIdx.x;
    int s = 0;
    for (int k = 0; k < nblk; ++k) s += bh[(size_t)k * NB + b];
    lds[b] = s;
    __syncthreads();
    for (int off = 1; off < NB; off <<= 1) {
        int v = (b >= off) ? lds[b - off] : 0;
        __syncthreads();
        lds[b] += v;
        __syncthreads();
    }
    int run = lds[b] - s;  // exclusive prefix
    bb[b] = run;
    if (b == NB - 1) bb[NB] = run + s;
    for (int k = 0; k < nblk; ++k) {
        const int c = bh[(size_t)k * NB + b];
        bm[(size_t)k * NB + b] = run;
        run += c;
    }
}

__global__ __launch_bounds__(256) void p1_scatter(const int* __restrict__ eiS,
                                                  const int* __restrict__ eiG,
                                                  const int* __restrict__ basem,
                                                  int2* __restrict__ pairs,
                                                  int E, int bsh, int nblk) {
    const int g = blockIdx.x / nblk;
    const int blk = blockIdx.x % nblk;
    const int* __restrict__ src = g ? eiG : eiS;
    const int* __restrict__ dst = src + E;
    int2* __restrict__ pr = pairs + (size_t)g * E;
    __shared__ int cur[NB];
    for (int i = threadIdx.x; i < NB; i += 256)
        cur[i] = basem[((size_t)(g * nblk + blk)) * NB + i];
    __syncthreads();
    const int base = blk * EPB;
    for (int k = 0; k < EPB; k += 256) {
        const int e = base + k + threadIdx.x;
        if (e < E) {
            const int d = dst[e];
            const int s = src[e];
            const int p = atomicAdd(&cur[d >> bsh], 1);
            pr[p] = make_int2(s, d);
        }
    }
}

__global__ __launch_bounds__(512) void p2_sort(const int2* __restrict__ pairs,
                                               const int* __restrict__ bucket_base,
                                               int* __restrict__ csr,
                                               int* __restrict__ row_start,
                                               int N, int E, int bsh) {
    __shared__ int cnt[BWMAX];
    __shared__ int off[BWMAX];
    const int g = blockIdx.x / NB;
    const int b = blockIdx.x % NB;
    const int bw = 1 << bsh;
    const int lo = b * bw;
    int nn = N - lo;
    if (nn <= 0) return;
    if (nn > bw) nn = bw;
    const int2* __restrict__ pr = pairs + (size_t)g * E;
    const int* __restrict__ bb = bucket_base + (size_t)g * (NB + 1);
    int* __restrict__ cs = csr + (size_t)g * E;
    int* __restrict__ rs = row_start + (size_t)g * (N + 1);
    const int tid = threadIdx.x;
    for (int i = tid; i < nn; i += 512) cnt[i] = 0;
    __syncthreads();
    const int e0 = bb[b];
    const int e1 = bb[b + 1];
    for (int e = e0 + tid; e < e1; e += 512)
        atomicAdd(&cnt[pr[e].y - lo], 1);
    __syncthreads();
    if (tid == 0) {
        int run = e0;
        for (int i = 0; i < nn; ++i) { off[i] = run; run += cnt[i]; }
    }
    __syncthreads();
    for (int i = tid; i < nn; i += 512) {
        rs[lo + i] = off[i];
        cnt[i] = off[i];  // reuse as cursor
    }
    if (lo + nn == N && tid == 0) rs[N] = e1;
    __syncthreads();
    for (int e = e0 + tid; e < e1; e += 512) {
        const int2 p = pr[e];
        const int pos = atomicAdd(&cnt[p.y - lo], 1);
        cs[pos] = p.x;
    }
}

// ---- fused dual-weight GEMM: Y = x@Wl, R = x@Wr -----------------------------
// 4 waves x 8 rows; both W tiles in LDS (broadcast reads, 2-way = free);
// x rows via wave-uniform pointers -> scalar/broadcast loads, off the LDS pipe.
template <int K>
__global__ __launch_bounds__(256) void gemm_fused(const float* __restrict__ x,
                                                  const float* __restrict__ Wl,
                                                  const float* __restrict__ Wr,
                                                  float* __restrict__ Y,
                                                  float* __restrict__ R, int n) {
    __shared__ float lds[2 * K * 64];
    const int tid = threadIdx.x;
    const int lane = tid & 63;
    {
        const float4* a = (const float4*)Wl;
        const float4* b = (const float4*)Wr;
        float4* d = (float4*)lds;
        for (int i = tid; i < K * 16; i += 256) {
            d[i] = a[i];
            d[K * 16 + i] = b[i];
        }
    }
    __syncthreads();

    const int rbase = __builtin_amdgcn_readfirstlane(blockIdx.x * 32 + (tid >> 6) * 8);
    const float* xr[8];
    #pragma unroll
    for (int r = 0; r < 8; ++r) {
        int row = rbase + r;
        if (row > n - 1) row = n - 1;
        xr[r] = x + (size_t)row * K;
    }
    float accY[8], accR[8];
    #pragma unroll
    for (int r = 0; r < 8; ++r) { accY[r] = 0.f; accR[r] = 0.f; }

    #pragma unroll 4
    for (int kc = 0; kc < K / 4; ++kc) {
        float wl[4], wr[4];
        #pragma unroll
        for (int t = 0; t < 4; ++t) {
            wl[t] = lds[(kc * 4 + t) * 64 + lane];
            wr[t] = lds[K * 64 + (kc * 4 + t) * 64 + lane];
        }
        #pragma unroll
        for (int r = 0; r < 8; ++r) {
            const float4 xv = *(const float4*)(xr[r] + kc * 4);
            accY[r] += xv.x * wl[0] + xv.y * wl[1] + xv.z * wl[2] + xv.w * wl[3];
            accR[r] += xv.x * wr[0] + xv.y * wr[1] + xv.z * wr[2] + xv.w * wr[3];
        }
    }
    #pragma unroll
    for (int r = 0; r < 8; ++r) {
        const int row = rbase + r;
        if (row < n) {
            Y[(size_t)row * 64 + lane] = accY[r];
            R[(size_t)row * 64 + lane] = accR[r];
        }
    }
}

// ---- aggregate + epilogue: H = relu(mean_csr(Y) + bl + R) -------------------
__global__ __launch_bounds__(256) void agg_fused(const float* __restrict__ Y,
                                                 const float* __restrict__ R,
                                                 const float* __restrict__ bl,
                                                 const int* __restrict__ csr,
                                                 const int* __restrict__ row_start,
                                                 float* __restrict__ H, int n) {
    const int wid = threadIdx.x >> 6;
    const int lane = threadIdx.x & 63;
    const int i = blockIdx.x * 4 + wid;
    if (i >= n) return;
    const int r0 = __builtin_amdgcn_readfirstlane(row_start[i]);
    const int r1 = __builtin_amdgcn_readfirstlane(row_start[i + 1]);
    float a[16];
    #pragma unroll
    for (int t = 0; t < 16; ++t) a[t] = 0.f;
    int e = r0;
    for (; e + 16 <= r1; e += 16) {
        #pragma unroll
        for (int t = 0; t < 16; ++t)
            a[t] += Y[(size_t)csr[e + t] * 64 + lane];
    }
    for (; e < r1; ++e) a[0] += Y[(size_t)csr[e] * 64 + lane];
    float acc = 0.f;
    #pragma unroll
    for (int t = 0; t < 16; ++t) acc += a[t];
    const int c = r1 - r0;
    const float sc = (c > 0) ? (1.0f / (float)c) : 1.0f;
    const float v = acc * sc + bl[lane] + R[(size_t)i * 64 + lane];
    H[(size_t)i * 64 + lane] = fmaxf(v, 0.0f);
}

// ---- pooling: PP partial blocks per graph (sorted batch, binary search) -----
__global__ __launch_bounds__(256) void pool_part(const float* __restrict__ H,
                                                 const int* __restrict__ batch,
                                                 float* __restrict__ parts,
                                                 int* __restrict__ pcnt, int n) {
    const int b = blockIdx.x / PP;
    const int p = blockIdx.x % PP;
    int lo = 0, hi = n;
    while (lo < hi) { int m = (lo + hi) >> 1; if (batch[m] < b) lo = m + 1; else hi = m; }
    const int beg = lo;
    hi = n;
    while (lo < hi) { int m = (lo + hi) >> 1; if (batch[m] < b + 1) lo = m + 1; else hi = m; }
    const int end = lo;
    const int len = end - beg;
    const int chunk = (len + PP - 1) / PP;
    const int s0 = beg + p * chunk;
    int s1 = s0 + chunk; if (s1 > end) s1 = end;

    const int wid = threadIdx.x >> 6;
    const int lane = threadIdx.x & 63;
    float acc = 0.f;
    for (int i = s0 + wid; i < s1; i += 4)
        acc += H[(size_t)i * 64 + lane];
    __shared__ float part[4][64];
    part[wid][lane] = acc;
    __syncthreads();
    if (wid == 0) {
        const float s = (part[0][lane] + part[1][lane]) + (part[2][lane] + part[3][lane]);
        parts[(size_t)(b * PP + p) * 64 + lane] = s;
        if (lane == 0 && p == 0) pcnt[b] = len;
    }
}

__global__ __launch_bounds__(128) void final_mlp(const float* __restrict__ partsS,
                                                 const int* __restrict__ cntS,
                                                 const float* __restrict__ partsG,
                                                 const int* __restrict__ cntG,
                                                 const float* __restrict__ depth,
                                                 const float* __restrict__ W1,
                                                 const float* __restrict__ b1,
                                                 const float* __restrict__ W2,
                                                 const float* __restrict__ b2,
                                                 float* __restrict__ out, int Bn) {
    __shared__ float lW1[129 * 64];
    __shared__ float red[128];
    const int t = threadIdx.x;
    for (int i = t; i < 129 * 64; i += 128) lW1[i] = W1[i];
    const float d = (t < Bn) ? depth[t] : 0.0f;
    red[t] = d;
    __syncthreads();
    for (int off = 64; off > 0; off >>= 1) {
        if (t < off) red[t] += red[t + off];
        __syncthreads();
    }
    const float mean = red[0] / (float)Bn;
    __syncthreads();
    const float dev = d - mean;
    red[t] = (t < Bn) ? dev * dev : 0.0f;
    __syncthreads();
    for (int off = 64; off > 0; off >>= 1) {
        if (t < off) red[t] += red[t + off];
        __syncthreads();
    }
    const float stdv = sqrtf(red[0] / (float)Bn);
    const float dn = dev / (stdv + 1e-6f);
    if (t >= Bn) return;

    float acc[64];
    #pragma unroll
    for (int j = 0; j < 64; ++j) acc[j] = b1[j];
    int cs = cntS[t]; if (cs < 1) cs = 1;
    int cg = cntG[t]; if (cg < 1) cg = 1;
    const float invS = 1.0f / (float)cs;
    const float invG = 1.0f / (float)cg;
    for (int k = 0; k < 64; ++k) {
        float fk = 0.f;
        #pragma unroll
        for (int p = 0; p < PP; ++p) fk += partsS[(size_t)(t * PP + p) * 64 + k];
        fk *= invS;
        #pragma unroll
        for (int j = 0; j < 64; ++j) acc[j] += fk * lW1[k * 64 + j];
    }
    for (int k = 0; k < 64; ++k) {
        float fk = 0.f;
        #pragma unroll
        for (int p = 0; p < PP; ++p) fk += partsG[(size_t)(t * PP + p) * 64 + k];
        fk *= invG;
        #pragma unroll
        for (int j = 0; j < 64; ++j) acc[j] += fk * lW1[(64 + k) * 64 + j];
    }
    #pragma unroll
    for (int j = 0; j < 64; ++j) acc[j] += dn * lW1[128 * 64 + j];
    float o = b2[0];
    #pragma unroll
    for (int j = 0; j < 64; ++j) o += fmaxf(acc[j], 0.0f) * W2[j];
    out[t] = o;
}

extern "C" void kernel_launch(void* const* d_in, const int* in_sizes, int n_in,
                              void* d_out, int out_size, void* d_ws, size_t ws_size,
                              hipStream_t stream) {
    const float* state_x     = (const float*)d_in[0];
    const int*   state_ei    = (const int*)d_in[1];
    const int*   state_batch = (const int*)d_in[2];
    const float* goal_x      = (const float*)d_in[3];
    const int*   goal_ei     = (const int*)d_in[4];
    const int*   goal_batch  = (const int*)d_in[5];
    const float* depth       = (const float*)d_in[6];
    const float* s1_Wl = (const float*)d_in[7];
    const float* s1_bl = (const float*)d_in[8];
    const float* s1_Wr = (const float*)d_in[9];
    const float* s2_Wl = (const float*)d_in[10];
    const float* s2_bl = (const float*)d_in[11];
    const float* s2_Wr = (const float*)d_in[12];
    const float* g1_Wl = (const float*)d_in[13];
    const float* g1_bl = (const float*)d_in[14];
    const float* g1_Wr = (const float*)d_in[15];
    const float* g2_Wl = (const float*)d_in[16];
    const float* g2_bl = (const float*)d_in[17];
    const float* g2_Wr = (const float*)d_in[18];
    const float* mlp_W1 = (const float*)d_in[19];
    const float* mlp_b1 = (const float*)d_in[20];
    const float* mlp_W2 = (const float*)d_in[21];
    const float* mlp_b2 = (const float*)d_in[22];

    const int N  = in_sizes[0] / 128;
    const int E  = in_sizes[1] / 2;
    const int Bn = in_sizes[6];
    const int nblk = (E + EPB - 1) / EPB;
    int bsh = 0;
    while (((size_t)NB << bsh) < (size_t)N) ++bsh;  // bucket width 2^bsh

    char* w = (char*)d_ws;
    auto alloc = [&](size_t bytes) {
        char* p = w;
        w += (bytes + 255) & ~(size_t)255;
        return p;
    };
    float* bufY        = (float*)alloc((size_t)N * 64 * sizeof(float));
    float* bufR        = (float*)alloc((size_t)N * 64 * sizeof(float));
    float* bufH        = (float*)alloc((size_t)N * 64 * sizeof(float));
    int*   csr         = (int*)alloc((size_t)2 * E * sizeof(int));
    int*   row_start   = (int*)alloc((size_t)2 * (N + 1) * sizeof(int));
    int*   blkhist     = (int*)alloc((size_t)2 * nblk * NB * sizeof(int));
    int*   basem       = (int*)alloc((size_t)2 * nblk * NB * sizeof(int));
    int*   bucket_base = (int*)alloc((size_t)2 * (NB + 1) * sizeof(int));
    float* partsS      = (float*)alloc((size_t)Bn * PP * 64 * sizeof(float));
    float* partsG      = (float*)alloc((size_t)Bn * PP * 64 * sizeof(float));
    int*   cntS        = (int*)alloc((size_t)Bn * sizeof(int));
    int*   cntG        = (int*)alloc((size_t)Bn * sizeof(int));
    int2*  pairs       = (int2*)bufY;  // aliases bufY+bufR (dead during CSR build)
    const size_t need = (size_t)(w - (char*)d_ws);
    const bool pairs_fit = (size_t)2 * E * sizeof(int2) <= (size_t)2 * N * 64 * sizeof(float);
    if (need > ws_size || (1 << bsh) > BWMAX || !pairs_fit) {
        hipMemsetAsync(d_out, 0, (size_t)out_size * sizeof(float), stream);
        return;
    }

    // ---- CSR build, both graphs ----
    p1_hist<<<2 * nblk, 256, 0, stream>>>(state_ei + E, goal_ei + E, blkhist, E, bsh, nblk);
    p1_scan<<<2, NB, 0, stream>>>(blkhist, basem, bucket_base, nblk);
    p1_scatter<<<2 * nblk, 256, 0, stream>>>(state_ei, goal_ei, basem, pairs, E, bsh, nblk);
    p2_sort<<<2 * NB, 512, 0, stream>>>(pairs, bucket_base, csr, row_start, N, E, bsh);

    const int g32 = (N + 31) / 32;
    const int g4  = (N + 3) / 4;
    const int* csrS = csr;
    const int* csrG = csr + E;
    const int* rsS  = row_start;
    const int* rsG  = row_start + (N + 1);

    // ---- state encoder ----
    gemm_fused<128><<<g32, 256, 0, stream>>>(state_x, s1_Wl, s1_Wr, bufY, bufR, N);
    agg_fused<<<g4, 256, 0, stream>>>(bufY, bufR, s1_bl, csrS, rsS, bufH, N);
    gemm_fused<64><<<g32, 256, 0, stream>>>(bufH, s2_Wl, s2_Wr, bufY, bufR, N);
    agg_fused<<<g4, 256, 0, stream>>>(bufY, bufR, s2_bl, csrS, rsS, bufH, N);
    pool_part<<<Bn * PP, 256, 0, stream>>>(bufH, state_batch, partsS, cntS, N);

    // ---- goal encoder ----
    gemm_fused<128><<<g32, 256, 0, stream>>>(goal_x, g1_Wl, g1_Wr, bufY, bufR, N);
    agg_fused<<<g4, 256, 0, stream>>>(bufY, bufR, g1_bl, csrG, rsG, bufH, N);
    gemm_fused<64><<<g32, 256, 0, stream>>>(bufH, g2_Wl, g2_Wr, bufY, bufR, N);
    agg_fused<<<g4, 256, 0, stream>>>(bufY, bufR, g2_bl, csrG, rsG, bufH, N);
    pool_part<<<Bn * PP, 256, 0, stream>>>(bufH, goal_batch, partsG, cntG, N);

    final_mlp<<<1, 128, 0, stream>>>(partsS, cntS, partsG, cntG, depth,
                                     mlp_W1, mlp_b1, mlp_W2, mlp_b2, (float*)d_out, Bn);
}